// Round 4
// baseline (196.560 us; speedup 1.0000x reference)
//
#include <hip/hip_runtime.h>

// DWT2d db4 — fully register-resident: no LDS, no barriers, no staging.
// Thread = one output column j, TI=8 output rows. Streams 22 patch rows;
// per row: 8-tap row filter -> (rlo, rhi) in regs, immediately accumulated
// into 32 register accumulators (4 subbands x 8 rows). 19 FMA/output.
// Wave = 64 consecutive j -> all loads/stores coalesced. Column wrap only
// for jt==3 blocks (block-uniform branch, 4x float2-mod path).
// x: (96, 512, 512) fp32 -> out: (96*4, 256, 256) fp32
// out[bc*4+s][i][j] = sum_{p,q} x[bc][(2i+p)%512][(2j+q)%512] * fH[s][p]*fW[s][q]

#define TI 8                // output rows per wave-tile
#define PR (2*TI + 6)       // 22 patch rows
#define HH 512
#define WW 512

typedef float float4u __attribute__((ext_vector_type(4), aligned(8)));
typedef float float2u __attribute__((ext_vector_type(2), aligned(8)));

template <bool CWRAP>
__device__ __forceinline__ void dwt_col(const float* __restrict__ xb,
                                        int rowBase, int c0,
                                        const float* flo, const float* fhi,
                                        float* ll, float* lh, float* hl, float* hh) {
#pragma unroll
    for (int r = 0; r < PR; ++r) {
        int gr = rowBase + r;          // wave-uniform (SALU)
        if (gr >= HH) gr -= HH;
        const float* xr = xb + gr * WW;
        float wv[8];
        if constexpr (!CWRAP) {
            float4u a = *(const float4u*)(xr + c0);
            float4u b = *(const float4u*)(xr + c0 + 4);
            wv[0] = a.x; wv[1] = a.y; wv[2] = a.z; wv[3] = a.w;
            wv[4] = b.x; wv[5] = b.y; wv[6] = b.z; wv[7] = b.w;
        } else {
#pragma unroll
            for (int k = 0; k < 4; ++k) {
                int c = c0 + 2 * k;    // even -> float2 never straddles wrap
                if (c >= WW) c -= WW;
                float2u v = *(const float2u*)(xr + c);
                wv[2 * k]     = v.x;
                wv[2 * k + 1] = v.y;
            }
        }
        float rlo = 0.f, rhi = 0.f;
#pragma unroll
        for (int q = 0; q < 8; ++q) { rlo += wv[q] * flo[q]; rhi += wv[q] * fhi[q]; }
        // column accumulation: row r feeds output i where r = 2i + p
#pragma unroll
        for (int p = (r & 1); p < 8; p += 2) {
            int d = r - p;
            if (d >= 0 && d < 2 * TI) {
                int i = d >> 1;
                float cl = flo[p], ch = fhi[p];
                ll[i] += rlo * cl; lh[i] += rlo * ch;
                hl[i] += rhi * cl; hh[i] += rhi * ch;
            }
        }
    }
}

__global__ __launch_bounds__(256)
void dwt2d_db4_kernel(const float* __restrict__ x,
                      const float* __restrict__ dec,
                      float* __restrict__ out) {
    const int tid  = threadIdx.x;
    const int lane = tid & 63;
    const int w    = tid >> 6;

    // XCD-stripe mapping: itb = n&7 -> XCD (hardware round-robin). XCD x owns
    // input rows [64x, 64x+70) of every image: halo-sharing tiles stay in-L2.
    const int n   = blockIdx.x;
    const int itb = n & 7;               // 0..7
    const int m   = n >> 3;
    const int jt  = m & 3;               // 0..3
    const int bc  = m >> 2;              // 0..95

    const int it = itb * 4 + w;          // 0..31 (wave-per-tile)
    const int j  = jt * 64 + lane;       // output column
    const int rowBase = it * (2 * TI);
    const int c0 = 2 * j;                // leftmost input col (8B-aligned)

    float flo[8], fhi[8];
#pragma unroll
    for (int k = 0; k < 8; ++k) { flo[k] = dec[k]; fhi[k] = dec[8 + k]; }

    const float* xb = x + (size_t)bc * HH * WW;

    float ll[TI], lh[TI], hl[TI], hh[TI];
#pragma unroll
    for (int i = 0; i < TI; ++i) { ll[i] = 0.f; lh[i] = 0.f; hl[i] = 0.f; hh[i] = 0.f; }

    if (jt < 3) dwt_col<false>(xb, rowBase, c0, flo, fhi, ll, lh, hl, hh);
    else        dwt_col<true >(xb, rowBase, c0, flo, fhi, ll, lh, hl, hh);

    // Stores: lane-consecutive j -> 256B coalesced per (i, subband).
    const size_t base = ((size_t)(bc * 4) * 256 + (size_t)it * TI) * 256 + j;
#pragma unroll
    for (int i = 0; i < TI; ++i) {
        __builtin_nontemporal_store(ll[i], &out[base + (size_t)i * 256]);
        __builtin_nontemporal_store(lh[i], &out[base + 1 * 65536 + (size_t)i * 256]);
        __builtin_nontemporal_store(hl[i], &out[base + 2 * 65536 + (size_t)i * 256]);
        __builtin_nontemporal_store(hh[i], &out[base + 3 * 65536 + (size_t)i * 256]);
    }
}

extern "C" void kernel_launch(void* const* d_in, const int* in_sizes, int n_in,
                              void* d_out, int out_size, void* d_ws, size_t ws_size,
                              hipStream_t stream) {
    const float* x   = (const float*)d_in[0];
    const float* dec = (const float*)d_in[1];
    float* out = (float*)d_out;

    dim3 grid(8 * 4 * 96);               // 3072 blocks (itb | jt | bc)
    dim3 block(256);                     // 4 waves, wave w -> it = itb*4+w
    dwt2d_db4_kernel<<<grid, block, 0, stream>>>(x, dec, out);
}

// Round 5
// 174.169 us; speedup vs baseline: 1.1286x; 1.1286x over previous
//
#include <hip/hip_runtime.h>

// DWT2d db4 — wave-autonomous tiles: NO barriers, no block lockstep.
// Each wave: DMA its private 14x134 patch -> own LDS slice (disjoint coalesced
// granules), wave-local vmcnt(0) wait, fused row+col pass in registers
// (x-windows read from LDS, where overlap is free), 16 outputs/lane stored.
// Filter taps packed as float2 {lo,hi} -> v_pk_fma_f32 (2 fp32 FMA/instr).
// x: (96, 512, 512) fp32 -> out: (96*4, 256, 256) fp32
// out[bc*4+s][i][j] = sum_{p,q} x[bc][(2i+p)%512][(2j+q)%512] * fH[s][p]*fW[s][q]

#define TI 4                 // output rows per wave-tile
#define PR (2*TI + 6)        // 14 patch rows
#define PC 136               // padded patch cols (need 134), 34 granules/row
#define NGW (PR * 34)        // 476 float4 granules per wave-patch
#define HH 512
#define WW 512

typedef float f2 __attribute__((ext_vector_type(2)));
typedef const __attribute__((address_space(1))) void gas_t;   // global
typedef __attribute__((address_space(3))) void las_t;         // LDS

__global__ __launch_bounds__(256)
void dwt2d_db4_kernel(const float* __restrict__ x,
                      const float* __restrict__ dec,
                      float* __restrict__ out) {
    __shared__ __align__(16) float patch[4][PR * PC];   // 4 x 7616 B = 30464 B -> 5 blocks/CU

    const int tid  = threadIdx.x;
    const int lane = tid & 63;
    const int w    = tid >> 6;

    // Tile decode. itb = n&7 -> XCD (hw round-robin): XCD x owns a contiguous
    // 64+6 input-row stripe per image -> halo-sharing tiles stay in its L2.
    const int n   = blockIdx.x;
    const int itb = n & 7;               // 0..7
    const int m   = n >> 3;
    const int s   = m & 1;               // which half of the XCD stripe
    const int jt  = (m >> 1) & 3;        // 0..3
    const int bc  = m >> 3;              // 0..95
    const int it  = (itb * 2 + s) * 4 + w;   // 0..63 (wave-private tile row)

    const int rowBase = it * (2 * TI);   // it*8
    const int colBase = jt * 128;

    // Packed taps: fp[q] = {flo[q], fhi[q]} -> every FMA is a pk_fma candidate.
    f2 fp[8];
#pragma unroll
    for (int k = 0; k < 8; ++k) fp[k] = f2{ dec[k], dec[8 + k] };

    const float* xb  = x + (size_t)bc * HH * WW;
    float*       smw = patch[w];

    // ---- DMA: 8 wave-batches of 16B granules into this wave's LDS slice.
    //      Fire-and-forget; wave-local drain (no s_barrier anywhere). ----
#pragma unroll
    for (int k = 0; k < 8; ++k) {
        int g = k * 64 + lane;                       // granule index in patch
        las_t* lp = (las_t*)((char*)smw + k * 1024); // wave-uniform; hw adds lane*16
        if (g < NGW) {
            int r  = g / 34;
            int c4 = g - r * 34;
            int gr = rowBase + r;      if (gr >= HH) gr -= HH;
            int gc = colBase + 4 * c4; if (gc >= WW) gc -= WW;  // 16B-aligned granule
            __builtin_amdgcn_global_load_lds((gas_t*)(xb + gr * WW + gc), lp, 16, 0, 0);
        }
    }
    asm volatile("s_waitcnt vmcnt(0)" ::: "memory");   // wave-local: other waves keep running
    __builtin_amdgcn_sched_barrier(0);

    // ---- Fused row+col pass, fully in registers. Lane = output column. ----
    f2 aL[TI], aH[TI];   // aL[i] = {LL, LH}, aH[i] = {HL, HH}
#pragma unroll
    for (int i = 0; i < TI; ++i) { aL[i] = f2{0.f, 0.f}; aH[i] = f2{0.f, 0.f}; }

#pragma unroll
    for (int r = 0; r < PR; ++r) {
        const f2* row = (const f2*)&smw[r * PC];     // 8B-aligned float2 view
        f2 a = row[lane];     f2 b = row[lane + 1];  // window x[2j .. 2j+7]
        f2 c = row[lane + 2]; f2 d = row[lane + 3];
        float wv[8] = { a.x, a.y, b.x, b.y, c.x, c.y, d.x, d.y };
        // row filter: rf = {lo, hi}, 8 pk_fma
        f2 rf = fp[0] * wv[0];
#pragma unroll
        for (int q = 1; q < 8; ++q) rf += fp[q] * wv[q];
        // col accumulate: row r feeds output i where r = 2i + p (p ascending
        // as r ascends -> same summation order as the two-phase reference)
#pragma unroll
        for (int p = (r & 1); p < 8; p += 2) {
            int dd = r - p;
            if (dd >= 0 && dd < 2 * TI) {
                int i = dd >> 1;
                aL[i] += fp[p] * rf.x;
                aH[i] += fp[p] * rf.y;
            }
        }
    }

    // ---- Stores: lane-consecutive -> 256B coalesced per (i, subband). ----
    const int oi = it * TI;
    const int oj = jt * 64 + lane;
    const size_t base = ((size_t)(bc * 4) * 256 + oi) * 256 + oj;
#pragma unroll
    for (int i = 0; i < TI; ++i) {
        __builtin_nontemporal_store(aL[i].x, &out[base + (size_t)i * 256]);
        __builtin_nontemporal_store(aL[i].y, &out[base + 1 * 65536 + (size_t)i * 256]);
        __builtin_nontemporal_store(aH[i].x, &out[base + 2 * 65536 + (size_t)i * 256]);
        __builtin_nontemporal_store(aH[i].y, &out[base + 3 * 65536 + (size_t)i * 256]);
    }
}

extern "C" void kernel_launch(void* const* d_in, const int* in_sizes, int n_in,
                              void* d_out, int out_size, void* d_ws, size_t ws_size,
                              hipStream_t stream) {
    const float* x   = (const float*)d_in[0];
    const float* dec = (const float*)d_in[1];
    float* out = (float*)d_out;

    dim3 grid(8 * 2 * 4 * 96);           // 6144 blocks = 24576 wave-tiles
    dim3 block(256);                     // 4 independent waves per block
    dwt2d_db4_kernel<<<grid, block, 0, stream>>>(x, dec, out);
}